// Round 7
// baseline (75.086 us; speedup 1.0000x reference)
//
#include <hip/hip_runtime.h>

#define KW 7
#define S 16               // output rows per band
#define NBANDS 32          // 512 / S
#define NROWS (S + KW - 1) // 22 input rows per band

typedef float vf4 __attribute__((ext_vector_type(4)));   // native vec for nontemporal store

// Thread t -> output cols 4t..4t+3 of one 16-row band. No LDS.
// Fully unrolled 22-row pipeline: 3-buffer load ring (prefetch distance 2),
// mod-7 accumulator ring (no shift movs), nontemporal output stores.

__global__ __launch_bounds__(128)
void conv7x7_kernel(const float* __restrict__ x, const float* __restrict__ w,
                    float* __restrict__ out) {
    const int W = 512, H = 512;
    const int bi   = blockIdx.x;
    const int n    = bi >> 5;
    const int band = bi & 31;
    const int y0   = band * S;

    const float* xn = x + (size_t)n * (W * H);
    float*       on = out + (size_t)n * (W * H);

    // Uniform weight reads -> scalar loads (SGPRs; verified R5: VGPR=52)
    float wr[49];
#pragma unroll
    for (int i = 0; i < 49; ++i) wr[i] = w[i];

    const int  t   = threadIdx.x;
    const int  cb  = t * 4;
    const bool ok0 = (cb >= 4);        // left halo chunk in-bounds
    const bool ok2 = (cb <= W - 8);    // right halo chunk in-bounds

    float acc[KW][4];                  // ring: output row o lives in acc[o % 7]
#pragma unroll
    for (int j = 0; j < KW; ++j)
#pragma unroll
        for (int c = 0; c < 4; ++c) acc[j][c] = 0.f;

    float v[3][12];                    // load ring: input row i in v[i % 3]

    // Load input row r (block-uniform r) into 12-float window: cols cb-4..cb+7
#define LOADROW(vbuf, r_)                                                      \
    {                                                                          \
        const int r__ = (r_);                                                  \
        if (r__ >= 0 && r__ < H) {                                             \
            const float* rp = xn + r__ * W + cb;                               \
            const float4 A = ok0 ? *reinterpret_cast<const float4*>(rp - 4)    \
                                 : make_float4(0.f, 0.f, 0.f, 0.f);            \
            const float4 B = *reinterpret_cast<const float4*>(rp);             \
            const float4 C = ok2 ? *reinterpret_cast<const float4*>(rp + 4)    \
                                 : make_float4(0.f, 0.f, 0.f, 0.f);            \
            vbuf[0]=A.x; vbuf[1]=A.y; vbuf[2]=A.z;  vbuf[3]=A.w;               \
            vbuf[4]=B.x; vbuf[5]=B.y; vbuf[6]=B.z;  vbuf[7]=B.w;               \
            vbuf[8]=C.x; vbuf[9]=C.y; vbuf[10]=C.z; vbuf[11]=C.w;              \
        } else {                                                               \
            _Pragma("unroll")                                                  \
            for (int q = 0; q < 12; ++q) vbuf[q] = 0.f;                        \
        }                                                                      \
    }

    // Prologue: rows 0 and 1 of the band's input range (y0-3, y0-2)
    LOADROW(v[0], y0 - 3)
    LOADROW(v[1], y0 - 2)

#pragma unroll
    for (int i = 0; i < NROWS; ++i) {
        // prefetch row i+2 (distance 2 ~= 800 issue-cycles of cover)
        if (i + 2 < NROWS) LOADROW(v[(i + 2) % 3], y0 + i - 1)

        // consume input row i: feeds outputs o = i-6 .. i (clamped to [0,S))
#pragma unroll
        for (int k = 0; k < KW; ++k) {
            const int o = i - k;               // output row; weight row = k
            if (o >= 0 && o < S) {
#pragma unroll
                for (int c = 0; c < 4; ++c)
#pragma unroll
                    for (int d = 0; d < KW; ++d)
                        acc[o % KW][c] += v[i % 3][1 + c + d] * wr[k * KW + d];
            }
        }

        // output row i-6 is complete: store (nontemporal) and recycle its slot
        if (i >= KW - 1) {
            const int o = i - (KW - 1);
            const int a = o % KW;
            vf4 val;
            val.x = acc[a][0]; val.y = acc[a][1];
            val.z = acc[a][2]; val.w = acc[a][3];
            __builtin_nontemporal_store(
                val, reinterpret_cast<vf4*>(on + (size_t)(y0 + o) * W + cb));
#pragma unroll
            for (int c = 0; c < 4; ++c) acc[a][c] = 0.f;
        }
    }

#undef LOADROW
}

extern "C" void kernel_launch(void* const* d_in, const int* in_sizes, int n_in,
                              void* d_out, int out_size, void* d_ws, size_t ws_size,
                              hipStream_t stream) {
    const float* x = (const float*)d_in[0];
    const float* w = (const float*)d_in[1];
    float* out = (float*)d_out;

    const int nblocks = 128 * NBANDS;   // 4096 blocks x 128 threads
    conv7x7_kernel<<<nblocks, 128, 0, stream>>>(x, w, out);
}

// Round 8
// 67.459 us; speedup vs baseline: 1.1131x; 1.1131x over previous
//
#include <hip/hip_runtime.h>

typedef float f2 __attribute__((ext_vector_type(2)));

#define KW 7
#define S 16               // output rows per band
#define NBANDS 32          // 512 / S

static __device__ __forceinline__ f2 mk(float a, float b) {
    f2 r; r.x = a; r.y = b; return r;
}

// Thread t -> output cols 4t..4t+3 (2 packed col-pairs) of one 16-row band.
// R5 skeleton (A/B row buffers, distance-1 prefetch, rolled x2 main loop),
// compute packed as v_pk_fma_f32 candidates: 98 pk-FMA/row vs 196 scalar.

__global__ __launch_bounds__(128)
void conv7x7_kernel(const float* __restrict__ x, const float* __restrict__ w,
                    float* __restrict__ out) {
    const int W = 512, H = 512;
    const int bi   = blockIdx.x;
    const int n    = bi >> 5;
    const int band = bi & 31;
    const int y0   = band * S;

    const float* xn = x + (size_t)n * (W * H);
    float*       on = out + (size_t)n * (W * H);

    // Uniform weight reads -> scalar loads (SGPRs)
    float wr[49];
#pragma unroll
    for (int i = 0; i < 49; ++i) wr[i] = w[i];

    const int  t   = threadIdx.x;
    const int  cb  = t * 4;
    const bool ok0 = (cb >= 4);        // left halo chunk in-bounds
    const bool ok2 = (cb <= W - 8);    // right halo chunk in-bounds

    // acc[j][p]: output row (next_store + j), col-pair p (cols 2p, 2p+1)
    f2 acc[KW][2];
#pragma unroll
    for (int j = 0; j < KW; ++j) { acc[j][0] = mk(0.f, 0.f); acc[j][1] = mk(0.f, 0.f); }

    // Window: 12 floats (cols cb-4..cb+7) as 6 aligned float2 per buffer
    f2 ea[6], eb[6];

#define LOADROW(E, r_)                                                         \
    {                                                                          \
        const int r__ = (r_);                                                  \
        if (r__ >= 0 && r__ < H) {                                             \
            const float* rp = xn + r__ * W + cb;                               \
            const float4 A = ok0 ? *reinterpret_cast<const float4*>(rp - 4)    \
                                 : make_float4(0.f, 0.f, 0.f, 0.f);            \
            const float4 B = *reinterpret_cast<const float4*>(rp);             \
            const float4 C = ok2 ? *reinterpret_cast<const float4*>(rp + 4)    \
                                 : make_float4(0.f, 0.f, 0.f, 0.f);            \
            E[0] = mk(A.x, A.y); E[1] = mk(A.z, A.w);                          \
            E[2] = mk(B.x, B.y); E[3] = mk(B.z, B.w);                          \
            E[4] = mk(C.x, C.y); E[5] = mk(C.z, C.w);                          \
        } else {                                                               \
            _Pragma("unroll")                                                  \
            for (int q = 0; q < 6; ++q) E[q] = mk(0.f, 0.f);                   \
        }                                                                      \
    }

    // Odd-offset pairs for the row being consumed (shared across all 7 k)
#define PREP(E)                                                                \
    const f2 od0 = mk(E[0].y, E[1].x);                                         \
    const f2 od1 = mk(E[1].y, E[2].x);                                         \
    const f2 od2 = mk(E[2].y, E[3].x);                                         \
    const f2 od3 = mk(E[3].y, E[4].x);                                         \
    const f2 od4 = mk(E[4].y, E[5].x);

    // acc[j_] += window * weight-row k_ : 14 packed FMAs
#define ACCUM(E, j_, k_)                                                       \
    {                                                                          \
        acc[j_][0] += od0  * wr[(k_)*7 + 0]; acc[j_][1] += od1  * wr[(k_)*7 + 0]; \
        acc[j_][0] += E[1] * wr[(k_)*7 + 1]; acc[j_][1] += E[2] * wr[(k_)*7 + 1]; \
        acc[j_][0] += od1  * wr[(k_)*7 + 2]; acc[j_][1] += od2  * wr[(k_)*7 + 2]; \
        acc[j_][0] += E[2] * wr[(k_)*7 + 3]; acc[j_][1] += E[3] * wr[(k_)*7 + 3]; \
        acc[j_][0] += od2  * wr[(k_)*7 + 4]; acc[j_][1] += od3  * wr[(k_)*7 + 4]; \
        acc[j_][0] += E[3] * wr[(k_)*7 + 5]; acc[j_][1] += E[4] * wr[(k_)*7 + 5]; \
        acc[j_][0] += od3  * wr[(k_)*7 + 6]; acc[j_][1] += od4  * wr[(k_)*7 + 6]; \
    }

    // Complete output row o_ (weight rows 6..0 against acc[0..6]), store, shift
#define MAIN(E, o_)                                                            \
    {                                                                          \
        PREP(E)                                                                \
        ACCUM(E, 0, 6) ACCUM(E, 1, 5) ACCUM(E, 2, 4) ACCUM(E, 3, 3)            \
        ACCUM(E, 4, 2) ACCUM(E, 5, 1) ACCUM(E, 6, 0)                           \
        const float4 val = make_float4(acc[0][0].x, acc[0][0].y,               \
                                       acc[0][1].x, acc[0][1].y);              \
        *reinterpret_cast<float4*>(on + (size_t)(o_) * W + cb) = val;          \
        _Pragma("unroll")                                                      \
        for (int j = 0; j < 6; ++j) {                                          \
            acc[j][0] = acc[j + 1][0]; acc[j][1] = acc[j + 1][1];              \
        }                                                                      \
        acc[6][0] = mk(0.f, 0.f); acc[6][1] = mk(0.f, 0.f);                    \
    }

    // ---- prologue: input rows y0-3 .. y0+2, pipelined A/B ----
    LOADROW(ea, y0 - 3)
    LOADROW(eb, y0 - 2)
    { PREP(ea) ACCUM(ea, 0, 0) }
    LOADROW(ea, y0 - 1)
    { PREP(eb) ACCUM(eb, 0, 1) ACCUM(eb, 1, 0) }
    LOADROW(eb, y0 + 0)
    { PREP(ea) ACCUM(ea, 0, 2) ACCUM(ea, 1, 1) ACCUM(ea, 2, 0) }
    LOADROW(ea, y0 + 1)
    { PREP(eb) ACCUM(eb, 0, 3) ACCUM(eb, 1, 2) ACCUM(eb, 2, 1) ACCUM(eb, 3, 0) }
    LOADROW(eb, y0 + 2)
    { PREP(ea) ACCUM(ea, 0, 4) ACCUM(ea, 1, 3) ACCUM(ea, 2, 2)
               ACCUM(ea, 3, 1) ACCUM(ea, 4, 0) }
    LOADROW(ea, y0 + 3)
    { PREP(eb) ACCUM(eb, 0, 5) ACCUM(eb, 1, 4) ACCUM(eb, 2, 3)
               ACCUM(eb, 3, 2) ACCUM(eb, 4, 1) ACCUM(eb, 5, 0) }

    // ---- main: 16 steps, A/B pipeline ----
    for (int s = 0; s < S; s += 2) {
        LOADROW(eb, y0 + 4 + s)              // row for step s+1
        MAIN(ea, y0 + s)
        if (s < S - 2) LOADROW(ea, y0 + 5 + s)   // row for step s+2
        MAIN(eb, y0 + s + 1)
    }

#undef LOADROW
#undef PREP
#undef ACCUM
#undef MAIN
}

extern "C" void kernel_launch(void* const* d_in, const int* in_sizes, int n_in,
                              void* d_out, int out_size, void* d_ws, size_t ws_size,
                              hipStream_t stream) {
    const float* x = (const float*)d_in[0];
    const float* w = (const float*)d_in[1];
    float* out = (float*)d_out;

    const int nblocks = 128 * NBANDS;   // 4096 blocks x 128 threads
    conv7x7_kernel<<<nblocks, 128, 0, stream>>>(x, w, out);
}